// Round 1
// baseline (249.396 us; speedup 1.0000x reference)
//
#include <hip/hip_runtime.h>
#include <math.h>

// EuclideanCodebook: N=131072 rows x d=128 fp32, K=1024 codes.
// bf16x3 split-precision MFMA (xh*eh + xl*eh + xh*el), per-row top-2 gap
// tracking, exact fp32 recheck of rows with gap < TAU.
// R2: 64 rows/wave spilled A-frags. Fixed: 32 rows.
// R3: dynamic ah[s] indexing -> cndmask waterfall. Fixed: full s-unroll.
// R5: 2 MFMA chains, 3 blocks/CU, transposed-codebook recheck.
// R6 (this round): codebook is L1/L2-resident (512 KB) -> LDS staging was
//     pure overhead (per-tile __syncthreads drained vmcnt(0)+lgkmcnt(0) with
//     only 2 waves/SIMD to cover; MfmaUtil 31% vs 41 us MFMA floor).
//     (a) B-fragments loaded straight global->VGPR from a frag-ordered
//         codebook (lane-contiguous 16B -> coalesced, L1/L2-hot); no LDS
//         staging, no draining barriers in the main loop. Raw s_barrier
//         (no waitcnt) per tile keeps the 4 waves tile-aligned for L1 reuse.
//     (b) x prescaled by 2 in the bf16 split + acc init = -||e||^2
//         (csq stored negated) -> epilogue drops the per-score fmaf.
//     (c) recheck fused into ecb_main tail (block-local LDS list) -> third
//         launch + global counter/list removed.
//     (d) prep re-parallelized: 16384 threads x 1 chunk, coalesced embed
//         reads, shfl-reduce for csq.

typedef __attribute__((ext_vector_type(8)))  short short8_t;   // 8 bf16
typedef __attribute__((ext_vector_type(16))) float floatx16;   // 32x32 C frag

constexpr int D        = 128;
constexpr int KCODES   = 1024;
constexpr int NTILES   = 32;      // 1024 / 32 codes-per-tile
constexpr int ROWS_BLK = 128;     // 4 waves x 32 rows
constexpr float TAU    = 0.015f;  // recheck margin >> 5-sigma score error (~2e-3)

// ws layout (bytes); total ~1.03 MB
constexpr size_t WS_NCSQ = 0;                      // 1024 f32, NEGATED ||e||^2
constexpr size_t WS_EHI  = 4096;                   // 1024*128 ushort, frag-ordered
constexpr size_t WS_ELO  = WS_EHI + 262144;
constexpr size_t WS_EMBT = WS_ELO + 262144;        // 128*1024 f32 transposed

__device__ inline unsigned short bf16_rne(float v, float* back) {
    unsigned u = __float_as_uint(v);
    unsigned r = (u + 0x7FFFu + ((u >> 16) & 1u)) >> 16;
    *back = __uint_as_float(r << 16);
    return (unsigned short)r;
}

// ------- prep: ncsq + frag-ordered bf16 hi/lo codebook + transposed codebook ----
// 64 blocks x 256 threads; thread = (code n, dim-chunk cc of 8 elements).
// Frag order: element offset ((t*8 + (cc>>1))*64 + (cc&1)*32 + (n&31)) * 8
// so main's lane l reads tile t, MFMA-step s at short8 index (t*8+s)*64 + l.
__global__ __launch_bounds__(256)
void ecb_prep(const float* __restrict__ embed, float* __restrict__ ncsq,
              unsigned short* __restrict__ ehi, unsigned short* __restrict__ elo,
              float* __restrict__ embT) {
    const int tid = threadIdx.x;
    const int cc = tid & 15;            // dim chunk 0..15
    const int nl = tid >> 4;            // 0..15
    const int n  = blockIdx.x * 16 + nl;
    const int t = n >> 5, nn = n & 31;
    const float* src = embed + (size_t)n * D + cc * 8;
    float4 a = *(const float4*)src;
    float4 b = *(const float4*)(src + 4);
    float vv[8] = {a.x, a.y, a.z, a.w, b.x, b.y, b.z, b.w};
    float ss = 0.f;
    unsigned short hq[8], lq[8];
#pragma unroll
    for (int j = 0; j < 8; ++j) {
        ss = fmaf(vv[j], vv[j], ss);
        float hb, db;
        hq[j] = bf16_rne(vv[j], &hb);
        lq[j] = bf16_rne(vv[j] - hb, &db);
    }
    uint4 ph, pl;
    ph.x = (unsigned)hq[0] | ((unsigned)hq[1] << 16);
    ph.y = (unsigned)hq[2] | ((unsigned)hq[3] << 16);
    ph.z = (unsigned)hq[4] | ((unsigned)hq[5] << 16);
    ph.w = (unsigned)hq[6] | ((unsigned)hq[7] << 16);
    pl.x = (unsigned)lq[0] | ((unsigned)lq[1] << 16);
    pl.y = (unsigned)lq[2] | ((unsigned)lq[3] << 16);
    pl.z = (unsigned)lq[4] | ((unsigned)lq[5] << 16);
    pl.w = (unsigned)lq[6] | ((unsigned)lq[7] << 16);
    size_t dst = ((size_t)(t * 8 + (cc >> 1)) * 64 + (size_t)((cc & 1) * 32 + nn)) * 8;
    *(uint4*)(ehi + dst) = ph;
    *(uint4*)(elo + dst) = pl;
#pragma unroll
    for (int j = 0; j < 8; ++j) embT[(size_t)(cc * 8 + j) * KCODES + n] = vv[j];
    // csq reduce over the 16 cc-lanes (contiguous within the wave)
#pragma unroll
    for (int m = 1; m < 16; m <<= 1) ss += __shfl_xor(ss, m, 64);
    if (cc == 0) ncsq[n] = -ss;
}

// ---------------- main: MFMA scores + argmax + fused exact recheck ----------------
__global__ __launch_bounds__(256, 2)
void ecb_main(const float* __restrict__ x,
              const unsigned short* __restrict__ ehi, const unsigned short* __restrict__ elo,
              const float* __restrict__ ncsq, const float* __restrict__ embed,
              const float* __restrict__ embT,
              float* __restrict__ out_idx, float* __restrict__ out_q) {
    __shared__ int   sidx[ROWS_BLK];
    __shared__ unsigned char llist[ROWS_BLK];
    __shared__ unsigned lcount;
    __shared__ float xs[D];
    __shared__ float bv[256];
    __shared__ int   bi[256];

    const int tid  = threadIdx.x;
    const int lane = tid & 63, wave = tid >> 6;
    const int col  = lane & 31, h = lane >> 5;
    const long rowblk = (long)blockIdx.x * ROWS_BLK;
    const int  roww   = wave * 32;

    if (tid == 0) lcount = 0u;

    // A prologue: 32 rows/wave of x -> bf16 hi/lo split of (2*x) in registers.
    short8_t ah[8], al[8];
    {
        const float* xr = x + (rowblk + roww + col) * (long)D + h * 8;
#pragma unroll
        for (int c = 0; c < 8; ++c) {
            float4 a  = *(const float4*)(xr + c * 16);
            float4 b  = *(const float4*)(xr + c * 16 + 4);
            float vv[8] = {a.x, a.y, a.z, a.w, b.x, b.y, b.z, b.w};
            short8_t fh, fl;
#pragma unroll
            for (int j = 0; j < 8; ++j) {
                float v2x = vv[j] + vv[j];    // fold the score's factor-2 into A
                float hb, db;
                fh[j] = (short)bf16_rne(v2x, &hb);
                fl[j] = (short)bf16_rne(v2x - hb, &db);
            }
            ah[c] = fh;
            al[c] = fl;
        }
    }

    float v1[16], v2[16];
#pragma unroll
    for (int j = 0; j < 16; ++j) { v1[j] = -INFINITY; v2[j] = -INFINITY; }

    const short8_t* Bh = (const short8_t*)ehi + lane;   // frag-ordered, coalesced
    const short8_t* Bl = (const short8_t*)elo + lane;

    __syncthreads();   // covers lcount init; aligns waves at loop entry

#pragma unroll 1
    for (int t = 0; t < NTILES; ++t) {
        const float negcs = ncsq[t * 32 + col];   // L1-hot 4 KB table
        short8_t bh[8], bl[8];
#pragma unroll
        for (int s = 0; s < 8; ++s) {             // 16 x global_load_dwordx4, L1/L2-hot
            bh[s] = Bh[(size_t)(t * 8 + s) * 64];
            bl[s] = Bl[(size_t)(t * 8 + s) * 64];
        }
        floatx16 accA, accB;                      // acc init = -||e||^2
#pragma unroll
        for (int i = 0; i < 16; ++i) { accA[i] = negcs; accB[i] = 0.f; }
#pragma unroll
        for (int s = 0; s < 8; ++s) {
            accA = __builtin_amdgcn_mfma_f32_32x32x16_bf16(ah[s], bh[s], accA, 0, 0, 0);
            accB = __builtin_amdgcn_mfma_f32_32x32x16_bf16(al[s], bh[s], accB, 0, 0, 0);
            accB = __builtin_amdgcn_mfma_f32_32x32x16_bf16(ah[s], bl[s], accB, 0, 0, 0);
        }
        // epilogue: score = 2 x.e - ||e||^2 already in accA+accB; tile id in LSBs
#pragma unroll
        for (int j = 0; j < 16; ++j) {
            float sc = accA[j] + accB[j];
            unsigned u = (__float_as_uint(sc) & ~31u) | (unsigned)t;
            float cand = __uint_as_float(u);
            float mn = fminf(v1[j], cand);
            v1[j] = fmaxf(v1[j], cand);
            v2[j] = fmaxf(v2[j], mn);
        }
        // raw barrier (NO waitcnt drain): keeps the block's 4 waves tile-aligned
        // so they share the 16 KB/tile B working set in L1. Loads stay in flight.
        __builtin_amdgcn_s_barrier();
    }

    // cross-lane top-2 merge over the 32 columns of each half
#pragma unroll
    for (int j = 0; j < 16; ++j) {
        float a1 = v1[j], a2 = v2[j];
        int   c1 = (int)((__float_as_uint(a1) & 31u) << 5) | col;   // tile*32 + col
#pragma unroll
        for (int m = 1; m < 32; m <<= 1) {
            float o1 = __shfl_xor(a1, m, 64);
            int   oc = __shfl_xor(c1, m, 64);
            float o2 = __shfl_xor(a2, m, 64);
            float lo = fminf(a1, o1);
            if (o1 > a1) { a1 = o1; c1 = oc; }
            a2 = fmaxf(fmaxf(a2, o2), lo);
        }
        if (col == j) {
            int row_local = roww + (j & 3) + 8 * (j >> 2) + 4 * h;
            sidx[row_local] = c1;
            out_idx[rowblk + row_local] = (float)c1;
            if (a1 - a2 < TAU) {                      // ties always land here
                unsigned p = atomicAdd(&lcount, 1u);  // <= 128 by construction
                llist[p] = (unsigned char)row_local;
            }
        }
    }
    __syncthreads();

    // gather quantize = embed[best] (exact fp32 values, L2-hot)
    for (int i = tid; i < ROWS_BLK * 32; i += 256) {
        int r = i >> 5, q = i & 31;
        int code = sidx[r];
        float4 ev = *(const float4*)(embed + (size_t)code * D + q * 4);
        *(float4*)(out_q + (rowblk + r) * (long)D + q * 4) = ev;
    }
    __syncthreads();

    // fused exact fp32 recheck of this block's flagged rows (k-sequential
    // accumulation order preserved from the standalone R4/R5 recheck kernel)
    const unsigned nf = lcount;
    const float4* eT = (const float4*)embT;   // [k][256 x float4-of-codes]
    for (unsigned f = 0; f < nf; ++f) {
        const int rl  = llist[f];
        const long row = rowblk + rl;
        if (tid < 32) *(float4*)&xs[tid * 4] = *(const float4*)(x + row * D + tid * 4);
        __syncthreads();
        float4 dot = {0.f, 0.f, 0.f, 0.f};
#pragma unroll 8
        for (int k = 0; k < D; ++k) {
            float xv = xs[k];
            float4 e = eT[(size_t)k * 256 + tid];
            dot.x = fmaf(xv, e.x, dot.x);
            dot.y = fmaf(xv, e.y, dot.y);
            dot.z = fmaf(xv, e.z, dot.z);
            dot.w = fmaf(xv, e.w, dot.w);
        }
        const int c0 = tid * 4;
        float scs[4] = {fmaf(2.f, dot.x, ncsq[c0]),
                        fmaf(2.f, dot.y, ncsq[c0 + 1]),
                        fmaf(2.f, dot.z, ncsq[c0 + 2]),
                        fmaf(2.f, dot.w, ncsq[c0 + 3])};
        float best = -INFINITY; int bidx = 0;
#pragma unroll
        for (int i = 0; i < 4; ++i)
            if (scs[i] > best) { best = scs[i]; bidx = c0 + i; }
        bv[tid] = best; bi[tid] = bidx;
        __syncthreads();
        for (int s = 128; s > 0; s >>= 1) {
            if (tid < s) {
                float ov = bv[tid + s]; int oi = bi[tid + s];
                if (ov > bv[tid] || (ov == bv[tid] && oi < bi[tid])) { bv[tid] = ov; bi[tid] = oi; }
            }
            __syncthreads();
        }
        const int win = bi[0];
        if (tid == 0) out_idx[row] = (float)win;
        if (tid < 32) {
            float4 ev = *(const float4*)(embed + (size_t)win * D + tid * 4);
            *(float4*)(out_q + row * D + tid * 4) = ev;
        }
        __syncthreads();
    }
}

extern "C" void kernel_launch(void* const* d_in, const int* in_sizes, int n_in,
                              void* d_out, int out_size, void* d_ws, size_t ws_size,
                              hipStream_t stream) {
    const float* x     = (const float*)d_in[0];
    const float* embed = (const float*)d_in[1];
    const int N = in_sizes[0] / D;   // 131072
    char* ws = (char*)d_ws;
    float*          ncsq = (float*)(ws + WS_NCSQ);
    unsigned short* ehi  = (unsigned short*)(ws + WS_EHI);
    unsigned short* elo  = (unsigned short*)(ws + WS_ELO);
    float*          embT = (float*)(ws + WS_EMBT);
    float* out_idx = (float*)d_out;
    float* out_q   = out_idx + N;

    hipLaunchKernelGGL(ecb_prep, dim3(64), dim3(256), 0, stream,
                       embed, ncsq, ehi, elo, embT);
    hipLaunchKernelGGL(ecb_main, dim3(N / ROWS_BLK), dim3(256), 0, stream,
                       x, ehi, elo, ncsq, embed, embT, out_idx, out_q);
}

// Round 2
// 239.245 us; speedup vs baseline: 1.0424x; 1.0424x over previous
//
#include <hip/hip_runtime.h>
#include <math.h>

// EuclideanCodebook: N=131072 rows x d=128 fp32, K=1024 codes.
// bf16x3 split-precision MFMA (xh*eh + xl*eh + xh*el), per-row top-2 gap
// tracking, exact fp32 recheck of rows with gap < TAU.
// R2: 64 rows/wave spilled A-frags. Fixed: 32 rows.
// R3: dynamic ah[s] indexing -> cndmask waterfall. Fixed: full s-unroll.
// R5: 2 MFMA chains, 3 blocks/CU. 141 us, MfmaUtil 31%.
// R6: dropped LDS staging for direct global->VGPR B loads. REGRESSED (174 us,
//     MfmaUtil 24%): per-wave B traffic (16KB/tile) exceeds L1 BW and the
//     loads lost all prefetch distance. LDS delivery (2.1M ds_read_b128
//     = 41 us floor) matches the MFMA floor (41 us) -- staging was right,
//     only the vmcnt(0) drain at __syncthreads was wrong.
// R7 (this round): R5 staging structure + m201 barrier discipline:
//     (a) double-buffered global_load_lds, raw s_barrier + counted
//         s_waitcnt vmcnt(4) -- stage(t+1) stays in flight across compute(t);
//         lgkmcnt(0)+barrier frees the buffer (no full drains in the loop).
//     (b) frag-linear codebook layout (from R6): LDS = byte-mirror of global,
//         reads are contiguous 1KB ds_read_b128, conflict-free, no swizzle.
//     (c) ncsq staged to LDS so the K-loop has NO VMEM except the 4 counted
//         stage loads (vmcnt arithmetic stays exact).
//     (d) s_setprio(1) around the MFMA cluster (independent blocks/CU).
//     (e) recheck scratch aliases ebuf -> 37.5 KB LDS.

typedef __attribute__((ext_vector_type(8)))  short short8_t;   // 8 bf16
typedef __attribute__((ext_vector_type(16))) float floatx16;   // 32x32 C frag

constexpr int D        = 128;
constexpr int KCODES   = 1024;
constexpr int NTILES   = 32;      // 1024 / 32 codes-per-tile
constexpr int ROWS_BLK = 128;     // 4 waves x 32 rows
constexpr float TAU    = 0.015f;  // recheck margin >> 5-sigma score error (~2e-3)

// ws layout (bytes); total ~1.03 MB
constexpr size_t WS_NCSQ = 0;                      // 1024 f32, NEGATED ||e||^2
constexpr size_t WS_EHI  = 4096;                   // 1024*128 ushort, frag-ordered
constexpr size_t WS_ELO  = WS_EHI + 262144;
constexpr size_t WS_EMBT = WS_ELO + 262144;        // 128*1024 f32 transposed

#define GLOBAL_AS __attribute__((address_space(1)))
#define LDS_AS    __attribute__((address_space(3)))

__device__ inline unsigned short bf16_rne(float v, float* back) {
    unsigned u = __float_as_uint(v);
    unsigned r = (u + 0x7FFFu + ((u >> 16) & 1u)) >> 16;
    *back = __uint_as_float(r << 16);
    return (unsigned short)r;
}

// ------- prep: ncsq + frag-ordered bf16 hi/lo codebook + transposed codebook ----
// 64 blocks x 256 threads; thread = (code n, dim-chunk cc of 8 elements).
// Frag order: short8 chunk index = (t*8 + (cc>>1))*64 + (cc&1)*32 + (n&31),
// so main's lane l reads tile t, MFMA-step s at short8 index (t*8+s)*64 + l.
__global__ __launch_bounds__(256)
void ecb_prep(const float* __restrict__ embed, float* __restrict__ ncsq,
              unsigned short* __restrict__ ehi, unsigned short* __restrict__ elo,
              float* __restrict__ embT) {
    const int tid = threadIdx.x;
    const int cc = tid & 15;            // dim chunk 0..15
    const int nl = tid >> 4;            // 0..15
    const int n  = blockIdx.x * 16 + nl;
    const int t = n >> 5, nn = n & 31;
    const float* src = embed + (size_t)n * D + cc * 8;
    float4 a = *(const float4*)src;
    float4 b = *(const float4*)(src + 4);
    float vv[8] = {a.x, a.y, a.z, a.w, b.x, b.y, b.z, b.w};
    float ss = 0.f;
    unsigned short hq[8], lq[8];
#pragma unroll
    for (int j = 0; j < 8; ++j) {
        ss = fmaf(vv[j], vv[j], ss);
        float hb, db;
        hq[j] = bf16_rne(vv[j], &hb);
        lq[j] = bf16_rne(vv[j] - hb, &db);
    }
    uint4 ph, pl;
    ph.x = (unsigned)hq[0] | ((unsigned)hq[1] << 16);
    ph.y = (unsigned)hq[2] | ((unsigned)hq[3] << 16);
    ph.z = (unsigned)hq[4] | ((unsigned)hq[5] << 16);
    ph.w = (unsigned)hq[6] | ((unsigned)hq[7] << 16);
    pl.x = (unsigned)lq[0] | ((unsigned)lq[1] << 16);
    pl.y = (unsigned)lq[2] | ((unsigned)lq[3] << 16);
    pl.z = (unsigned)lq[4] | ((unsigned)lq[5] << 16);
    pl.w = (unsigned)lq[6] | ((unsigned)lq[7] << 16);
    size_t dst = ((size_t)(t * 8 + (cc >> 1)) * 64 + (size_t)((cc & 1) * 32 + nn)) * 8;
    *(uint4*)(ehi + dst) = ph;
    *(uint4*)(elo + dst) = pl;
#pragma unroll
    for (int j = 0; j < 8; ++j) embT[(size_t)(cc * 8 + j) * KCODES + n] = vv[j];
    // csq reduce over the 16 cc-lanes (contiguous within the wave)
#pragma unroll
    for (int m = 1; m < 16; m <<= 1) ss += __shfl_xor(ss, m, 64);
    if (cc == 0) ncsq[n] = -ss;
}

// ---------------- main: MFMA scores + argmax + fused exact recheck ----------------
__global__ __launch_bounds__(256, 3)
void ecb_main(const float* __restrict__ x,
              const unsigned short* __restrict__ ehi, const unsigned short* __restrict__ elo,
              const float* __restrict__ ncsq, const float* __restrict__ embed,
              const float* __restrict__ embT,
              float* __restrict__ out_idx, float* __restrict__ out_q) {
    __shared__ short8_t ebuf[2][2][512];   // [dbuf][hi/lo][s*64+lane], 32 KB
    __shared__ float ncsq_s[KCODES];       // 4 KB
    __shared__ int   sidx[ROWS_BLK];
    __shared__ unsigned char llist[ROWS_BLK];
    __shared__ unsigned lcount;

    const int tid  = threadIdx.x;
    const int lane = tid & 63, wave = tid >> 6;
    const int col  = lane & 31, h = lane >> 5;
    const long rowblk = (long)blockIdx.x * ROWS_BLK;
    const int  roww   = wave * 32;

    if (tid == 0) lcount = 0u;
    ((float4*)ncsq_s)[tid] = ((const float4*)ncsq)[tid];   // 1024 f32 -> LDS

    // A prologue: 32 rows/wave of x -> bf16 hi/lo split of (2*x) in registers.
    short8_t ah[8], al[8];
    {
        const float* xr = x + (rowblk + roww + col) * (long)D + h * 8;
#pragma unroll
        for (int c = 0; c < 8; ++c) {
            float4 a  = *(const float4*)(xr + c * 16);
            float4 b  = *(const float4*)(xr + c * 16 + 4);
            float vv[8] = {a.x, a.y, a.z, a.w, b.x, b.y, b.z, b.w};
            short8_t fh, fl;
#pragma unroll
            for (int j = 0; j < 8; ++j) {
                float v2x = vv[j] + vv[j];    // fold the score's factor-2 into A
                float hb, db;
                fh[j] = (short)bf16_rne(v2x, &hb);
                fl[j] = (short)bf16_rne(v2x - hb, &db);
            }
            ah[c] = fh;
            al[c] = fl;
        }
    }

    auto stage = [&](int t, int bb) {
        const char* gh = (const char*)ehi + (size_t)t * 8192;
        const char* gl = (const char*)elo + (size_t)t * 8192;
        char* lh = (char*)&ebuf[bb][0][0];
        char* ll = (char*)&ebuf[bb][1][0];
        const int off = wave * 2048;
        // 4 x global_load_lds_dwordx4 per wave = the exact vmcnt(4) quantum
        __builtin_amdgcn_global_load_lds((const GLOBAL_AS unsigned int*)(gh + off + lane * 16),
                                         (LDS_AS unsigned int*)(lh + off), 16, 0, 0);
        __builtin_amdgcn_global_load_lds((const GLOBAL_AS unsigned int*)(gh + off + 1024 + lane * 16),
                                         (LDS_AS unsigned int*)(lh + off + 1024), 16, 0, 0);
        __builtin_amdgcn_global_load_lds((const GLOBAL_AS unsigned int*)(gl + off + lane * 16),
                                         (LDS_AS unsigned int*)(ll + off), 16, 0, 0);
        __builtin_amdgcn_global_load_lds((const GLOBAL_AS unsigned int*)(gl + off + 1024 + lane * 16),
                                         (LDS_AS unsigned int*)(ll + off + 1024), 16, 0, 0);
    };

    float v1[16], v2[16];
#pragma unroll
    for (int j = 0; j < 16; ++j) { v1[j] = -INFINITY; v2[j] = -INFINITY; }

    __syncthreads();          // ncsq_s + lcount visible (one full drain, prologue only)
    stage(0, 0);              // issue tile 0; NOT drained here

#pragma unroll 1
    for (int t = 0; t < NTILES; ++t) {
        const int b = t & 1;
        if (t + 1 < NTILES) {
            stage(t + 1, b ^ 1);                             // 4 more loads in flight
            asm volatile("s_waitcnt vmcnt(4)" ::: "memory"); // stage(t) done (mine)
        } else {
            asm volatile("s_waitcnt vmcnt(0)" ::: "memory"); // last tile: drain
        }
        __builtin_amdgcn_sched_barrier(0);
        __builtin_amdgcn_s_barrier();                        // stage(t) done (all waves)

        const float negcs = ncsq_s[t * 32 + col];            // LDS, conflict-free
        floatx16 accA, accB;                                 // acc init = -||e||^2
#pragma unroll
        for (int i = 0; i < 16; ++i) { accA[i] = negcs; accB[i] = 0.f; }

        __builtin_amdgcn_s_setprio(1);
#pragma unroll
        for (int s = 0; s < 8; ++s) {
            short8_t bh = ebuf[b][0][s * 64 + lane];         // ds_read_b128, 1KB/wave
            short8_t bl = ebuf[b][1][s * 64 + lane];
            accA = __builtin_amdgcn_mfma_f32_32x32x16_bf16(ah[s], bh, accA, 0, 0, 0);
            accB = __builtin_amdgcn_mfma_f32_32x32x16_bf16(al[s], bh, accB, 0, 0, 0);
            accB = __builtin_amdgcn_mfma_f32_32x32x16_bf16(ah[s], bl, accB, 0, 0, 0);
        }
        __builtin_amdgcn_s_setprio(0);

        // epilogue: score = 2 x.e - ||e||^2 already in accA+accB; tile id in LSBs
#pragma unroll
        for (int j = 0; j < 16; ++j) {
            float sc = accA[j] + accB[j];
            unsigned u = (__float_as_uint(sc) & ~31u) | (unsigned)t;
            float cand = __uint_as_float(u);
            float mn = fminf(v1[j], cand);
            v1[j] = fmaxf(v1[j], cand);
            v2[j] = fmaxf(v2[j], mn);
        }

        asm volatile("s_waitcnt lgkmcnt(0)" ::: "memory");   // my ds_reads of buf[t] done
        __builtin_amdgcn_sched_barrier(0);
        __builtin_amdgcn_s_barrier();                        // buf[t] free for stage(t+2)
    }

    // cross-lane top-2 merge over the 32 columns of each half
#pragma unroll
    for (int j = 0; j < 16; ++j) {
        float a1 = v1[j], a2 = v2[j];
        int   c1 = (int)((__float_as_uint(a1) & 31u) << 5) | col;   // tile*32 + col
#pragma unroll
        for (int m = 1; m < 32; m <<= 1) {
            float o1 = __shfl_xor(a1, m, 64);
            int   oc = __shfl_xor(c1, m, 64);
            float o2 = __shfl_xor(a2, m, 64);
            float lo = fminf(a1, o1);
            if (o1 > a1) { a1 = o1; c1 = oc; }
            a2 = fmaxf(fmaxf(a2, o2), lo);
        }
        if (col == j) {
            int row_local = roww + (j & 3) + 8 * (j >> 2) + 4 * h;
            sidx[row_local] = c1;
            out_idx[rowblk + row_local] = (float)c1;
            if (a1 - a2 < TAU) {                      // ties always land here
                unsigned p = atomicAdd(&lcount, 1u);  // <= 128 by construction
                llist[p] = (unsigned char)row_local;
            }
        }
    }
    __syncthreads();

    // gather quantize = embed[best] (exact fp32 values, L2-hot)
    for (int i = tid; i < ROWS_BLK * 32; i += 256) {
        int r = i >> 5, q = i & 31;
        int code = sidx[r];
        float4 ev = *(const float4*)(embed + (size_t)code * D + q * 4);
        *(float4*)(out_q + (rowblk + r) * (long)D + q * 4) = ev;
    }
    __syncthreads();

    // fused exact fp32 recheck of this block's flagged rows (k-sequential
    // accumulation order preserved). Scratch aliases ebuf (loop is done).
    float* xs = (float*)&ebuf[0][0][0];          // 128 f32
    float* bv = xs + D;                           // 256 f32
    int*   bi = (int*)(bv + 256);                 // 256 i32
    const unsigned nf = lcount;
    const float4* eT = (const float4*)embT;       // [k][256 x float4-of-codes]
    for (unsigned f = 0; f < nf; ++f) {
        const int rl  = llist[f];
        const long row = rowblk + rl;
        if (tid < 32) *(float4*)&xs[tid * 4] = *(const float4*)(x + row * D + tid * 4);
        __syncthreads();
        float4 dot = {0.f, 0.f, 0.f, 0.f};
#pragma unroll 8
        for (int k = 0; k < D; ++k) {
            float xv = xs[k];
            float4 e = eT[(size_t)k * 256 + tid];
            dot.x = fmaf(xv, e.x, dot.x);
            dot.y = fmaf(xv, e.y, dot.y);
            dot.z = fmaf(xv, e.z, dot.z);
            dot.w = fmaf(xv, e.w, dot.w);
        }
        const int c0 = tid * 4;
        float scs[4] = {fmaf(2.f, dot.x, ncsq_s[c0]),
                        fmaf(2.f, dot.y, ncsq_s[c0 + 1]),
                        fmaf(2.f, dot.z, ncsq_s[c0 + 2]),
                        fmaf(2.f, dot.w, ncsq_s[c0 + 3])};
        float best = -INFINITY; int bidx = 0;
#pragma unroll
        for (int i = 0; i < 4; ++i)
            if (scs[i] > best) { best = scs[i]; bidx = c0 + i; }
        bv[tid] = best; bi[tid] = bidx;
        __syncthreads();
        for (int s = 128; s > 0; s >>= 1) {
            if (tid < s) {
                float ov = bv[tid + s]; int oi = bi[tid + s];
                if (ov > bv[tid] || (ov == bv[tid] && oi < bi[tid])) { bv[tid] = ov; bi[tid] = oi; }
            }
            __syncthreads();
        }
        const int win = bi[0];
        if (tid == 0) out_idx[row] = (float)win;
        if (tid < 32) {
            float4 ev = *(const float4*)(embed + (size_t)win * D + tid * 4);
            *(float4*)(out_q + row * D + tid * 4) = ev;
        }
        __syncthreads();
    }
}

extern "C" void kernel_launch(void* const* d_in, const int* in_sizes, int n_in,
                              void* d_out, int out_size, void* d_ws, size_t ws_size,
                              hipStream_t stream) {
    const float* x     = (const float*)d_in[0];
    const float* embed = (const float*)d_in[1];
    const int N = in_sizes[0] / D;   // 131072
    char* ws = (char*)d_ws;
    float*          ncsq = (float*)(ws + WS_NCSQ);
    unsigned short* ehi  = (unsigned short*)(ws + WS_EHI);
    unsigned short* elo  = (unsigned short*)(ws + WS_ELO);
    float*          embT = (float*)(ws + WS_EMBT);
    float* out_idx = (float*)d_out;
    float* out_q   = out_idx + N;

    hipLaunchKernelGGL(ecb_prep, dim3(64), dim3(256), 0, stream,
                       embed, ncsq, ehi, elo, embT);
    hipLaunchKernelGGL(ecb_main, dim3(N / ROWS_BLK), dim3(256), 0, stream,
                       x, ehi, elo, ncsq, embed, embT, out_idx, out_q);
}